// Round 4
// baseline (731.586 us; speedup 1.0000x reference)
//
#include <hip/hip_runtime.h>
#include <hip/hip_bf16.h>
#include <math.h>

#define EMBED 1024
#define NHEADS 16
#define HDIM 64
#define BATCH 4
#define SQL 1024
#define SKL 2048

typedef unsigned short u16;
typedef __attribute__((ext_vector_type(4))) float f32x4;
typedef __attribute__((ext_vector_type(8))) __bf16 bf16x8;
typedef __attribute__((ext_vector_type(8))) short s16x8;
typedef __attribute__((ext_vector_type(8))) u16 u16x8;

__device__ __forceinline__ u16 f2bf(float x) {
    __hip_bfloat16 h = __float2bfloat16(x);
    return *reinterpret_cast<u16*>(&h);
}
__device__ __forceinline__ float bf2f(u16 u) {
    __hip_bfloat16 h;
    *reinterpret_cast<u16*>(&h) = u;
    return __bfloat162float(h);
}
__device__ __forceinline__ f32x4 mfma16(s16x8 a, s16x8 b, f32x4 c) {
    return __builtin_amdgcn_mfma_f32_16x16x32_bf16(
        __builtin_bit_cast(bf16x8, a), __builtin_bit_cast(bf16x8, b), c, 0, 0, 0);
}

// ---------------------------------------------------------------------------
// GEMM NT (unchanged): Y[M,N] = A[M,K] * W[N,K]^T + bias. K=1024.
// ---------------------------------------------------------------------------
template<int SPLIT, int A_BF16, int OUT_MODE>
__global__ __launch_bounds__(256)
void gemm_mfma(const void* __restrict__ Ap, const float* __restrict__ Wp,
               const float* __restrict__ bias,
               void* __restrict__ Y0p, void* __restrict__ Y1p,
               int M, int N) {
    const int K = 1024;
    __shared__ u16 sA[2][128 * 40];
    __shared__ u16 sB[2][128 * 40];

    const int t = threadIdx.x;
    const int lane = t & 63;
    const int w = t >> 6;
    const int wm = w >> 1, wn = w & 1;
    const int rowBase = blockIdx.y * 128;
    const int colBase = blockIdx.x * 128;
    const int srow = t >> 1;
    const int sc = (t & 1) * 16;

    const float* Af = (const float*)Ap;
    const u16* Au = (const u16*)Ap;

    f32x4 acc[4][4];
#pragma unroll
    for (int i = 0; i < 4; ++i)
#pragma unroll
        for (int j = 0; j < 4; ++j) acc[i][j] = (f32x4){0.f, 0.f, 0.f, 0.f};

    float ax[16], bx[16];
    u16x8 au0, au1;

    {
        const int k0 = 0;
        if constexpr (A_BF16) {
            au0 = *(const u16x8*)&Au[(size_t)(rowBase + srow) * K + k0 + sc];
            au1 = *(const u16x8*)&Au[(size_t)(rowBase + srow) * K + k0 + sc + 8];
        } else {
#pragma unroll
            for (int j = 0; j < 4; ++j)
                *(float4*)&ax[j * 4] = *(const float4*)&Af[(size_t)(rowBase + srow) * K + k0 + sc + j * 4];
        }
#pragma unroll
        for (int j = 0; j < 4; ++j)
            *(float4*)&bx[j * 4] = *(const float4*)&Wp[(size_t)(colBase + srow) * K + k0 + sc + j * 4];
    }

    for (int k0 = 0; k0 < K; k0 += 32) {
        __syncthreads();
        {
            u16x8 h0, h1, l0, l1;
            if constexpr (A_BF16) {
                h0 = au0; h1 = au1;
            } else {
#pragma unroll
                for (int j = 0; j < 8; ++j) {
                    h0[j] = f2bf(ax[j]); h1[j] = f2bf(ax[j + 8]);
                    if constexpr (SPLIT) {
                        l0[j] = f2bf(ax[j] - bf2f(h0[j]));
                        l1[j] = f2bf(ax[j + 8] - bf2f(h1[j]));
                    }
                }
            }
            *(u16x8*)&sA[0][srow * 40 + sc] = h0;
            *(u16x8*)&sA[0][srow * 40 + sc + 8] = h1;
            if constexpr (SPLIT) {
                *(u16x8*)&sA[1][srow * 40 + sc] = l0;
                *(u16x8*)&sA[1][srow * 40 + sc + 8] = l1;
            }
            u16x8 bh0, bh1, bl0, bl1;
#pragma unroll
            for (int j = 0; j < 8; ++j) {
                bh0[j] = f2bf(bx[j]); bh1[j] = f2bf(bx[j + 8]);
                if constexpr (SPLIT) {
                    bl0[j] = f2bf(bx[j] - bf2f(bh0[j]));
                    bl1[j] = f2bf(bx[j + 8] - bf2f(bh1[j]));
                }
            }
            *(u16x8*)&sB[0][srow * 40 + sc] = bh0;
            *(u16x8*)&sB[0][srow * 40 + sc + 8] = bh1;
            if constexpr (SPLIT) {
                *(u16x8*)&sB[1][srow * 40 + sc] = bl0;
                *(u16x8*)&sB[1][srow * 40 + sc + 8] = bl1;
            }
        }
        __syncthreads();
        if (k0 + 32 < K) {
            const int kn = k0 + 32;
            if constexpr (A_BF16) {
                au0 = *(const u16x8*)&Au[(size_t)(rowBase + srow) * K + kn + sc];
                au1 = *(const u16x8*)&Au[(size_t)(rowBase + srow) * K + kn + sc + 8];
            } else {
#pragma unroll
                for (int j = 0; j < 4; ++j)
                    *(float4*)&ax[j * 4] = *(const float4*)&Af[(size_t)(rowBase + srow) * K + kn + sc + j * 4];
            }
#pragma unroll
            for (int j = 0; j < 4; ++j)
                *(float4*)&bx[j * 4] = *(const float4*)&Wp[(size_t)(colBase + srow) * K + kn + sc + j * 4];
        }
        {
            s16x8 afh[4], afl[4], bfh[4], bfl[4];
#pragma unroll
            for (int mi = 0; mi < 4; ++mi) {
                int ar = wm * 64 + mi * 16 + (lane & 15);
                int ai = ar * 40 + (lane >> 4) * 8;
                afh[mi] = *(const s16x8*)&sA[0][ai];
                if constexpr (SPLIT) afl[mi] = *(const s16x8*)&sA[1][ai];
            }
#pragma unroll
            for (int ni = 0; ni < 4; ++ni) {
                int br = wn * 64 + ni * 16 + (lane & 15);
                int bi = br * 40 + (lane >> 4) * 8;
                bfh[ni] = *(const s16x8*)&sB[0][bi];
                if constexpr (SPLIT) bfl[ni] = *(const s16x8*)&sB[1][bi];
            }
#pragma unroll
            for (int mi = 0; mi < 4; ++mi)
#pragma unroll
                for (int ni = 0; ni < 4; ++ni) {
                    acc[mi][ni] = mfma16(afh[mi], bfh[ni], acc[mi][ni]);
                    if constexpr (SPLIT) {
                        acc[mi][ni] = mfma16(afh[mi], bfl[ni], acc[mi][ni]);
                        acc[mi][ni] = mfma16(afl[mi], bfh[ni], acc[mi][ni]);
                    }
                }
        }
    }

#pragma unroll
    for (int mi = 0; mi < 4; ++mi)
#pragma unroll
        for (int ni = 0; ni < 4; ++ni)
#pragma unroll
            for (int rr = 0; rr < 4; ++rr) {
                int mg = rowBase + wm * 64 + mi * 16 + (lane >> 4) * 4 + rr;
                int ng = colBase + wn * 64 + ni * 16 + (lane & 15);
                float y = acc[mi][ni][rr];
                if constexpr (OUT_MODE == 0) {
                    ((float*)Y0p)[(size_t)mg * N + ng] = y + bias[ng];
                } else if constexpr (OUT_MODE == 1) {
                    y += bias[ng];
                    u16 h = f2bf(y);
                    ((u16*)Y0p)[(size_t)mg * N + ng] = h;
                    ((u16*)Y1p)[(size_t)mg * N + ng] = f2bf(y - bf2f(h));
                } else {
                    y += bias[mg];
                    ((u16*)Y0p)[(size_t)mg * N + ng] = f2bf(y);
                }
            }
}

// ---------------------------------------------------------------------------
// Fused attention, register-direct K/V. Grid = 512: block = (b, qtile, hhalf).
// blockIdx = qtile*8 + (hhalf*4 + b)  ->  each (b,hhalf) group maps to one XCD
// (blockIdx%8 round-robin), so the group's K/V stream stays in that XCD's L2.
// Each block: 8 heads, 16 q-rows, k-chunks of 128; mean partial in registers;
// hhalf=0 writes meanOut, hhalf=1 writes part1 (combined by mean_combine).
// attOut aliases Qhi (disjoint per-head column lifetimes within each block).
// ---------------------------------------------------------------------------
#define CH 128
#define NCH 16

#define LOADK(d0, d1, d2, d3, c) { \
    size_t _o = kbase0 + (size_t)(c) * (CH * EMBED); \
    d0 = *(const s16x8*)&Khi[_o];      d1 = *(const s16x8*)&Khi[_o + 32]; \
    d2 = *(const s16x8*)&Klo[_o];      d3 = *(const s16x8*)&Klo[_o + 32]; }

#define LOADV(d0, d1, c) { \
    size_t _o = vbase0 + (size_t)(c) * CH; \
    d0 = *(const s16x8*)&VT[_o]; \
    d1 = *(const s16x8*)&VT[_o + (size_t)16 * (BATCH * SKL)]; }

#define CHUNK(c, k0, k1, k2, k3, v0, v1) { \
    f32x4 s = {0.f, 0.f, 0.f, 0.f}; \
    s = mfma16(qh0, k0, s); \
    s = mfma16(qh1, k1, s); \
    s = mfma16(qh0, k2, s); \
    s = mfma16(qh1, k3, s); \
    s = mfma16(ql0, k0, s); \
    s = mfma16(ql1, k1, s); \
    _Pragma("unroll") \
    for (int r4 = 0; r4 < 4; ++r4) { \
        int q = qg * 4 + r4; \
        float e = __expf(s[r4] * 0.125f); \
        ev[r4][c] = e; \
        sP[(c) & 1][q * 128 + ((pch ^ (q & 7)) << 3) + plow] = f2bf(e); \
    } \
    asm volatile("s_waitcnt lgkmcnt(0)" ::: "memory"); \
    __builtin_amdgcn_sched_barrier(0); \
    __builtin_amdgcn_s_barrier(); \
    __builtin_amdgcn_sched_barrier(0); \
    { \
        s16x8 pa = *(const s16x8*)&sP[(c) & 1][pidx]; \
        pv0 = mfma16(pa, v0, pv0); \
        pv1 = mfma16(pa, v1, pv1); \
    } }

__global__ __launch_bounds__(512, 4)
void attn_mfma(const u16* Qhi, const u16* __restrict__ Qlo,
               const u16* __restrict__ Khi, const u16* __restrict__ Klo,
               const u16* __restrict__ VT, u16* attOut,
               float* __restrict__ meanOut, float* __restrict__ part1) {
    __shared__ u16 sP[2][16 * 128];      // 8 KB
    __shared__ float sAtt[4][16 * 64];   // 16 KB
    __shared__ float sL[8][16];

    const int t = threadIdx.x;
    const int w = t >> 6;
    const int lane = t & 63;
    const int qg = lane >> 4;       // 0..3
    const int c16 = lane & 15;
    const int g = blockIdx.x & 7;   // XCD group
    const int b = g & 3;
    const int hh = g >> 2;
    const int qbase = (blockIdx.x >> 3) * 16;
    const int ks = w >> 1;          // PV k-slice 0..3
    const int dh2 = w & 1;          // PV d-half

    const int pcol = w * 16 + c16;
    const int pch = pcol >> 3;
    const int plow = pcol & 7;
    const int pidx = c16 * 128 + (((ks * 4 + qg) ^ (c16 & 7)) << 3);

    float meanacc[4][NCH];
#pragma unroll
    for (int r4 = 0; r4 < 4; ++r4)
#pragma unroll
        for (int c = 0; c < NCH; ++c) meanacc[r4][c] = 0.f;

    for (int h = hh * 8; h < hh * 8 + 8; ++h) {
        // Q fragments (A-frag: q-row = c16, k-pos = qg*8+j, d = dh*32+qg*8+j)
        size_t qoff = (size_t)(b * SQL + qbase + c16) * EMBED + h * HDIM + qg * 8;
        s16x8 qh0 = *(const s16x8*)&Qhi[qoff];
        s16x8 qh1 = *(const s16x8*)&Qhi[qoff + 32];
        s16x8 ql0 = *(const s16x8*)&Qlo[qoff];
        s16x8 ql1 = *(const s16x8*)&Qlo[qoff + 32];

        const size_t kbase0 = (size_t)(b * SKL + w * 16 + c16) * EMBED + h * HDIM + qg * 8;
        const size_t vbase0 = (size_t)(h * HDIM + dh2 * 32 + c16) * (size_t)(BATCH * SKL)
                              + (size_t)b * SKL + ks * 32 + qg * 8;

        f32x4 pv0 = {0.f, 0.f, 0.f, 0.f}, pv1 = {0.f, 0.f, 0.f, 0.f};
        float ev[4][NCH];

        s16x8 ka0, ka1, ka2, ka3, kb0, kb1, kb2, kb3;
        s16x8 va0, va1, vb0, vb1;

        LOADK(ka0, ka1, ka2, ka3, 0)
        LOADV(va0, va1, 0)

#pragma unroll
        for (int cc = 0; cc < NCH; cc += 2) {
            LOADK(kb0, kb1, kb2, kb3, cc + 1)
            LOADV(vb0, vb1, cc + 1)
            CHUNK(cc, ka0, ka1, ka2, ka3, va0, va1)
            if (cc + 2 < NCH) {
                LOADK(ka0, ka1, ka2, ka3, cc + 2)
                LOADV(va0, va1, cc + 2)
            }
            CHUNK(cc + 1, kb0, kb1, kb2, kb3, vb0, vb1)
        }

        // ---- head epilogue: l reduce over the 16 k-lanes of each wave
        {
            float ls[4];
#pragma unroll
            for (int r4 = 0; r4 < 4; ++r4) {
                float v = 0.f;
#pragma unroll
                for (int c = 0; c < NCH; ++c) v += ev[r4][c];
#pragma unroll
                for (int m = 1; m <= 8; m <<= 1) v += __shfl_xor(v, m, 64);
                ls[r4] = v;
            }
            if (c16 == 0) {
#pragma unroll
                for (int r4 = 0; r4 < 4; ++r4) sL[w][qg * 4 + r4] = ls[r4];
            }
        }
#pragma unroll
        for (int r4 = 0; r4 < 4; ++r4) {
            sAtt[ks][(qg * 4 + r4) * 64 + dh2 * 32 + c16] = pv0[r4];
            sAtt[ks][(qg * 4 + r4) * 64 + dh2 * 32 + 16 + c16] = pv1[r4];
        }
        __syncthreads();
        {
            int q = t >> 5;
            int d0 = (t & 31) * 2;
            float l = sL[0][q] + sL[1][q] + sL[2][q] + sL[3][q] +
                      sL[4][q] + sL[5][q] + sL[6][q] + sL[7][q];
            float linv = 1.f / l;
            float a0 = sAtt[0][q * 64 + d0] + sAtt[1][q * 64 + d0] +
                       sAtt[2][q * 64 + d0] + sAtt[3][q * 64 + d0];
            float a1 = sAtt[0][q * 64 + d0 + 1] + sAtt[1][q * 64 + d0 + 1] +
                       sAtt[2][q * 64 + d0 + 1] + sAtt[3][q * 64 + d0 + 1];
            size_t o = (size_t)(b * SQL + qbase + q) * EMBED + h * HDIM + d0;
            attOut[o] = f2bf(a0 * linv);
            attOut[o + 1] = f2bf(a1 * linv);
        }
#pragma unroll
        for (int r4 = 0; r4 < 4; ++r4) {
            int q = qg * 4 + r4;
            float l = sL[0][q] + sL[1][q] + sL[2][q] + sL[3][q] +
                      sL[4][q] + sL[5][q] + sL[6][q] + sL[7][q];
            float linv = 1.f / l;
#pragma unroll
            for (int c = 0; c < NCH; ++c) meanacc[r4][c] += ev[r4][c] * linv;
        }
        __syncthreads();   // sL/sAtt consumed before next head overwrites
    }

    // ---- final partial-mean write (already scaled by 1/16)
    float* mtgt = hh ? part1 : meanOut;
    const float s16c = 1.f / 16.f;
#pragma unroll
    for (int r4 = 0; r4 < 4; ++r4)
#pragma unroll
        for (int c = 0; c < NCH; ++c)
            mtgt[(size_t)(b * SQL + qbase + qg * 4 + r4) * SKL + c * CH + w * 16 + c16] =
                meanacc[r4][c] * s16c;
}

// ---------------------------------------------------------------------------
__global__ __launch_bounds__(256)
void mean_combine(float* __restrict__ m, const float* __restrict__ p, int n4) {
    int i = blockIdx.x * 256 + threadIdx.x;
    const int stride = gridDim.x * 256;
    for (; i < n4; i += stride) {
        float4 a = ((float4*)m)[i];
        float4 b = ((const float4*)p)[i];
        a.x += b.x; a.y += b.y; a.z += b.z; a.w += b.w;
        ((float4*)m)[i] = a;
    }
}

// ---------------------------------------------------------------------------
extern "C" void kernel_launch(void* const* d_in, const int* in_sizes, int n_in,
                              void* d_out, int out_size, void* d_ws, size_t ws_size,
                              hipStream_t stream) {
    const float* query = (const float*)d_in[0];
    const float* key   = (const float*)d_in[1];
    const float* value = (const float*)d_in[2];
    const float* Wq = (const float*)d_in[3];
    const float* bq = (const float*)d_in[4];
    const float* Wk = (const float*)d_in[5];
    const float* bk = (const float*)d_in[6];
    const float* Wv = (const float*)d_in[7];
    const float* bv = (const float*)d_in[8];
    const float* Wo = (const float*)d_in[9];
    const float* bo = (const float*)d_in[10];

    float* out = (float*)d_out;                         // [4,1024,1024]
    float* meanOut = out + (size_t)BATCH * SQL * EMBED; // [4,1024,2048]

    u16* Qhi = (u16*)d_ws;                              // [4096][1024] bf16 (aliased by Att)
    u16* Qlo = Qhi + (size_t)4096 * 1024;
    u16* Khi = Qlo + (size_t)4096 * 1024;               // [8192][1024]
    u16* Klo = Khi + (size_t)8192 * 1024;
    u16* VTw = Klo + (size_t)8192 * 1024;               // [1024][8192] (V^T)
    float* part1 = (float*)(VTw + (size_t)1024 * 8192); // [4,1024,2048] f32 partial
    u16* Att = Qhi;                                     // alias: per-head cols reused

    gemm_mfma<1, 0, 1><<<dim3(8, 32), 256, 0, stream>>>(query, Wq, bq, Qhi, Qlo, 4096, 1024);
    gemm_mfma<1, 0, 1><<<dim3(8, 64), 256, 0, stream>>>(key, Wk, bk, Khi, Klo, 8192, 1024);
    gemm_mfma<0, 0, 2><<<dim3(64, 8), 256, 0, stream>>>(Wv, value, bv, VTw, nullptr, 1024, 8192);
    attn_mfma<<<dim3(512), dim3(512), 0, stream>>>(Qhi, Qlo, Khi, Klo, VTw, Att, meanOut, part1);
    mean_combine<<<dim3(2048), dim3(256), 0, stream>>>(meanOut, part1, (BATCH * SQL * SKL) / 4);
    gemm_mfma<0, 1, 0><<<dim3(8, 32), 256, 0, stream>>>(Att, Wo, bo, out, nullptr, 4096, 1024);
}

// Round 5
// 704.061 us; speedup vs baseline: 1.0391x; 1.0391x over previous
//
#include <hip/hip_runtime.h>
#include <hip/hip_bf16.h>
#include <math.h>

#define EMBED 1024
#define NHEADS 16
#define HDIM 64
#define BATCH 4
#define SQL 1024
#define SKL 2048

typedef unsigned short u16;
typedef __attribute__((ext_vector_type(4))) float f32x4;
typedef __attribute__((ext_vector_type(8))) __bf16 bf16x8;
typedef __attribute__((ext_vector_type(4))) __bf16 bf16x4;
typedef __attribute__((ext_vector_type(8))) short s16x8;
typedef __attribute__((ext_vector_type(4))) short s16x4;
typedef __attribute__((ext_vector_type(8))) u16 u16x8;

__device__ __forceinline__ u16 f2bf(float x) {
    __hip_bfloat16 h = __float2bfloat16(x);
    return *reinterpret_cast<u16*>(&h);
}
__device__ __forceinline__ float bf2f(u16 u) {
    __hip_bfloat16 h;
    *reinterpret_cast<u16*>(&h) = u;
    return __bfloat162float(h);
}
__device__ __forceinline__ f32x4 mfma16(s16x8 a, s16x8 b, f32x4 c) {
    return __builtin_amdgcn_mfma_f32_16x16x32_bf16(
        __builtin_bit_cast(bf16x8, a), __builtin_bit_cast(bf16x8, b), c, 0, 0, 0);
}
__device__ __forceinline__ f32x4 mfma16k16(s16x4 a, s16x4 b, f32x4 c) {
    return __builtin_amdgcn_mfma_f32_16x16x16bf16_1k(a, b, c, 0, 0, 0);
}

// ---------------------------------------------------------------------------
// GEMM NT (unchanged): Y[M,N] = A[M,K] * W[N,K]^T + bias. K=1024.
// ---------------------------------------------------------------------------
template<int SPLIT, int A_BF16, int OUT_MODE>
__global__ __launch_bounds__(256)
void gemm_mfma(const void* __restrict__ Ap, const float* __restrict__ Wp,
               const float* __restrict__ bias,
               void* __restrict__ Y0p, void* __restrict__ Y1p,
               int M, int N) {
    const int K = 1024;
    __shared__ u16 sA[2][128 * 40];
    __shared__ u16 sB[2][128 * 40];

    const int t = threadIdx.x;
    const int lane = t & 63;
    const int w = t >> 6;
    const int wm = w >> 1, wn = w & 1;
    const int rowBase = blockIdx.y * 128;
    const int colBase = blockIdx.x * 128;
    const int srow = t >> 1;
    const int sc = (t & 1) * 16;

    const float* Af = (const float*)Ap;
    const u16* Au = (const u16*)Ap;

    f32x4 acc[4][4];
#pragma unroll
    for (int i = 0; i < 4; ++i)
#pragma unroll
        for (int j = 0; j < 4; ++j) acc[i][j] = (f32x4){0.f, 0.f, 0.f, 0.f};

    float ax[16], bx[16];
    u16x8 au0, au1;

    {
        const int k0 = 0;
        if constexpr (A_BF16) {
            au0 = *(const u16x8*)&Au[(size_t)(rowBase + srow) * K + k0 + sc];
            au1 = *(const u16x8*)&Au[(size_t)(rowBase + srow) * K + k0 + sc + 8];
        } else {
#pragma unroll
            for (int j = 0; j < 4; ++j)
                *(float4*)&ax[j * 4] = *(const float4*)&Af[(size_t)(rowBase + srow) * K + k0 + sc + j * 4];
        }
#pragma unroll
        for (int j = 0; j < 4; ++j)
            *(float4*)&bx[j * 4] = *(const float4*)&Wp[(size_t)(colBase + srow) * K + k0 + sc + j * 4];
    }

    for (int k0 = 0; k0 < K; k0 += 32) {
        __syncthreads();
        {
            u16x8 h0, h1, l0, l1;
            if constexpr (A_BF16) {
                h0 = au0; h1 = au1;
            } else {
#pragma unroll
                for (int j = 0; j < 8; ++j) {
                    h0[j] = f2bf(ax[j]); h1[j] = f2bf(ax[j + 8]);
                    if constexpr (SPLIT) {
                        l0[j] = f2bf(ax[j] - bf2f(h0[j]));
                        l1[j] = f2bf(ax[j + 8] - bf2f(h1[j]));
                    }
                }
            }
            *(u16x8*)&sA[0][srow * 40 + sc] = h0;
            *(u16x8*)&sA[0][srow * 40 + sc + 8] = h1;
            if constexpr (SPLIT) {
                *(u16x8*)&sA[1][srow * 40 + sc] = l0;
                *(u16x8*)&sA[1][srow * 40 + sc + 8] = l1;
            }
            u16x8 bh0, bh1, bl0, bl1;
#pragma unroll
            for (int j = 0; j < 8; ++j) {
                bh0[j] = f2bf(bx[j]); bh1[j] = f2bf(bx[j + 8]);
                if constexpr (SPLIT) {
                    bl0[j] = f2bf(bx[j] - bf2f(bh0[j]));
                    bl1[j] = f2bf(bx[j + 8] - bf2f(bh1[j]));
                }
            }
            *(u16x8*)&sB[0][srow * 40 + sc] = bh0;
            *(u16x8*)&sB[0][srow * 40 + sc + 8] = bh1;
            if constexpr (SPLIT) {
                *(u16x8*)&sB[1][srow * 40 + sc] = bl0;
                *(u16x8*)&sB[1][srow * 40 + sc + 8] = bl1;
            }
        }
        __syncthreads();
        if (k0 + 32 < K) {
            const int kn = k0 + 32;
            if constexpr (A_BF16) {
                au0 = *(const u16x8*)&Au[(size_t)(rowBase + srow) * K + kn + sc];
                au1 = *(const u16x8*)&Au[(size_t)(rowBase + srow) * K + kn + sc + 8];
            } else {
#pragma unroll
                for (int j = 0; j < 4; ++j)
                    *(float4*)&ax[j * 4] = *(const float4*)&Af[(size_t)(rowBase + srow) * K + kn + sc + j * 4];
            }
#pragma unroll
            for (int j = 0; j < 4; ++j)
                *(float4*)&bx[j * 4] = *(const float4*)&Wp[(size_t)(colBase + srow) * K + kn + sc + j * 4];
        }
        {
            s16x8 afh[4], afl[4], bfh[4], bfl[4];
#pragma unroll
            for (int mi = 0; mi < 4; ++mi) {
                int ar = wm * 64 + mi * 16 + (lane & 15);
                int ai = ar * 40 + (lane >> 4) * 8;
                afh[mi] = *(const s16x8*)&sA[0][ai];
                if constexpr (SPLIT) afl[mi] = *(const s16x8*)&sA[1][ai];
            }
#pragma unroll
            for (int ni = 0; ni < 4; ++ni) {
                int br = wn * 64 + ni * 16 + (lane & 15);
                int bi = br * 40 + (lane >> 4) * 8;
                bfh[ni] = *(const s16x8*)&sB[0][bi];
                if constexpr (SPLIT) bfl[ni] = *(const s16x8*)&sB[1][bi];
            }
#pragma unroll
            for (int mi = 0; mi < 4; ++mi)
#pragma unroll
                for (int ni = 0; ni < 4; ++ni) {
                    acc[mi][ni] = mfma16(afh[mi], bfh[ni], acc[mi][ni]);
                    if constexpr (SPLIT) {
                        acc[mi][ni] = mfma16(afh[mi], bfl[ni], acc[mi][ni]);
                        acc[mi][ni] = mfma16(afl[mi], bfh[ni], acc[mi][ni]);
                    }
                }
        }
    }

#pragma unroll
    for (int mi = 0; mi < 4; ++mi)
#pragma unroll
        for (int ni = 0; ni < 4; ++ni)
#pragma unroll
            for (int rr = 0; rr < 4; ++rr) {
                int mg = rowBase + wm * 64 + mi * 16 + (lane >> 4) * 4 + rr;
                int ng = colBase + wn * 64 + ni * 16 + (lane & 15);
                float y = acc[mi][ni][rr];
                if constexpr (OUT_MODE == 0) {
                    ((float*)Y0p)[(size_t)mg * N + ng] = y + bias[ng];
                } else if constexpr (OUT_MODE == 1) {
                    y += bias[ng];
                    u16 h = f2bf(y);
                    ((u16*)Y0p)[(size_t)mg * N + ng] = h;
                    ((u16*)Y1p)[(size_t)mg * N + ng] = f2bf(y - bf2f(h));
                } else {
                    y += bias[mg];
                    ((u16*)Y0p)[(size_t)mg * N + ng] = f2bf(y);
                }
            }
}

// ---------------------------------------------------------------------------
// Fused attention, barrier-free inner loop via swapped-operand MFMA.
// Block = (b, qtile of 16 rows), 512 thr (8 waves), grid 256 (1 block/CU).
// Wave w privately owns k-slab [w*256, w*256+256), split into 16 subchunks
// of 16 k. Per subchunk: QK^T as mfma(A=K, B=Q) -> D[k][q] (lane = one q,
// 4 k's), exp, pack bf16 -> pb (which IS the PV B-frag), PV as O^T with
// v_mfma_f32_16x16x16_bf16 (A=V^T). No LDS, no barrier inside the k-loop.
// Per head: 2 barriers for cross-wave l and O^T reduction. pb[16] doubles
// as the e-store for mean accumulation (registers).
// ---------------------------------------------------------------------------
#define LOADKV(buf, sc) { \
    size_t _kr = (size_t)(b * SKL + kslab + (sc) * 16 + c16) * EMBED + h * HDIM + g * 8; \
    kh0[buf] = *(const s16x8*)&Khi[_kr];      kh1[buf] = *(const s16x8*)&Khi[_kr + 32]; \
    kl0[buf] = *(const s16x8*)&Klo[_kr];      kl1[buf] = *(const s16x8*)&Klo[_kr + 32]; \
    size_t _vc = (size_t)(b * SKL) + kslab + (sc) * 16 + g * 4; \
    _Pragma("unroll") \
    for (int mi = 0; mi < 4; ++mi) \
        vv[buf][mi] = *(const s16x4*)&VT[(size_t)(h * HDIM + mi * 16 + c16) * (BATCH * SKL) + _vc]; }

__global__ __launch_bounds__(512, 2)
void attn_mfma(const u16* Qhi, const u16* __restrict__ Qlo,
               const u16* __restrict__ Khi, const u16* __restrict__ Klo,
               const u16* __restrict__ VT, u16* attOut,
               float* __restrict__ meanOut) {
    __shared__ float sAtt[8][1028];   // per-wave O^T partial [d*16+q], padded
    __shared__ float sL[8][16];

    const int t = threadIdx.x;
    const int w = t >> 6;
    const int lane = t & 63;
    const int g = lane >> 4;        // k-group / kk-group
    const int c16 = lane & 15;      // q index (QK D-col, PV D-col); d-row (V A-frag); k-row (K A-frag)
    const int b = blockIdx.x >> 6;
    const int qbase = (blockIdx.x & 63) * 16;
    const int kslab = w * 256;

    float meanacc[16][4];           // [subchunk][r4] for q=c16, k=kslab+sc*16+g*4+r4
#pragma unroll
    for (int sc = 0; sc < 16; ++sc)
#pragma unroll
        for (int r = 0; r < 4; ++r) meanacc[sc][r] = 0.f;

    for (int h = 0; h < NHEADS; ++h) {
        // Q B-frags: B[kk=d][n=q]: lane holds Q[q=c16][d=g*8+j] (+32 for d-half 1)
        size_t qoff = (size_t)(b * SQL + qbase + c16) * EMBED + h * HDIM + g * 8;
        s16x8 qh0 = *(const s16x8*)&Qhi[qoff];
        s16x8 qh1 = *(const s16x8*)&Qhi[qoff + 32];
        s16x8 ql0 = *(const s16x8*)&Qlo[qoff];
        s16x8 ql1 = *(const s16x8*)&Qlo[qoff + 32];

        f32x4 oacc[4];
#pragma unroll
        for (int mi = 0; mi < 4; ++mi) oacc[mi] = (f32x4){0.f, 0.f, 0.f, 0.f};
        float lsum = 0.f;
        s16x4 pb[16];

        s16x8 kh0[2], kh1[2], kl0[2], kl1[2];
        s16x4 vv[2][4];

        LOADKV(0, 0)
#pragma unroll
        for (int sc = 0; sc < 16; ++sc) {
            const int cur = sc & 1;
            if (sc + 1 < 16) LOADKV(cur ^ 1, sc + 1)
            // QK^T swapped: D[k][q] = K·Q^T ; split-bf16: Khi·Qhi + Khi·Qlo + Klo·Qhi
            f32x4 s = {0.f, 0.f, 0.f, 0.f};
            s = mfma16(kh0[cur], qh0, s);
            s = mfma16(kh1[cur], qh1, s);
            s = mfma16(kh0[cur], ql0, s);
            s = mfma16(kh1[cur], ql1, s);
            s = mfma16(kl0[cur], qh0, s);
            s = mfma16(kl1[cur], qh1, s);
            // e = exp(s/8); lane holds q=c16, k = kslab+sc*16+g*4+r
            float e0 = __expf(s[0] * 0.125f);
            float e1 = __expf(s[1] * 0.125f);
            float e2 = __expf(s[2] * 0.125f);
            float e3 = __expf(s[3] * 0.125f);
            lsum += (e0 + e1) + (e2 + e3);
            s16x4 p;
            p[0] = (short)f2bf(e0); p[1] = (short)f2bf(e1);
            p[2] = (short)f2bf(e2); p[3] = (short)f2bf(e3);
            pb[sc] = p;
            // PV: O^T[d][q] += V^T-frag · P-frag  (16x16x16)
#pragma unroll
            for (int mi = 0; mi < 4; ++mi)
                oacc[mi] = mfma16k16(vv[cur][mi], p, oacc[mi]);
        }

        // ---- cross-wave reduction: l and O^T partials
        lsum += __shfl_xor(lsum, 16, 64);
        lsum += __shfl_xor(lsum, 32, 64);
        if (g == 0) sL[w][c16] = lsum;
#pragma unroll
        for (int mi = 0; mi < 4; ++mi)
#pragma unroll
            for (int r = 0; r < 4; ++r)
                sAtt[w][(mi * 16 + g * 4 + r) * 16 + c16] = oacc[mi][r];
        __syncthreads();

        // ---- attended epilogue: O[q][d] = (Σw O^T_w[d][q]) / l[q]
#pragma unroll
        for (int rep = 0; rep < 2; ++rep) {
            int idx = rep * 512 + t;
            int d = idx & 63;
            int q = idx >> 6;
            float l = sL[0][q] + sL[1][q] + sL[2][q] + sL[3][q] +
                      sL[4][q] + sL[5][q] + sL[6][q] + sL[7][q];
            float o = sAtt[0][d * 16 + q] + sAtt[1][d * 16 + q] +
                      sAtt[2][d * 16 + q] + sAtt[3][d * 16 + q] +
                      sAtt[4][d * 16 + q] + sAtt[5][d * 16 + q] +
                      sAtt[6][d * 16 + q] + sAtt[7][d * 16 + q];
            attOut[(size_t)(b * SQL + qbase + q) * EMBED + h * HDIM + d] = f2bf(o / l);
        }

        // ---- mean accumulation from pb (registers), q=c16
        {
            float lq = sL[0][c16] + sL[1][c16] + sL[2][c16] + sL[3][c16] +
                       sL[4][c16] + sL[5][c16] + sL[6][c16] + sL[7][c16];
            float linv = 1.f / lq;
#pragma unroll
            for (int sc = 0; sc < 16; ++sc) {
                s16x4 p = pb[sc];
                meanacc[sc][0] += bf2f((u16)p[0]) * linv;
                meanacc[sc][1] += bf2f((u16)p[1]) * linv;
                meanacc[sc][2] += bf2f((u16)p[2]) * linv;
                meanacc[sc][3] += bf2f((u16)p[3]) * linv;
            }
        }
        __syncthreads();   // sAtt/sL consumed before next head overwrites
    }

    // ---- final mean write: q=c16, k = kslab + sc*16 + g*4 + r
    const float s16c = 1.f / 16.f;
#pragma unroll
    for (int sc = 0; sc < 16; ++sc) {
        f32x4 m;
#pragma unroll
        for (int r = 0; r < 4; ++r) m[r] = meanacc[sc][r] * s16c;
        *(f32x4*)&meanOut[(size_t)(b * SQL + qbase + c16) * SKL + kslab + sc * 16 + g * 4] = m;
    }
}

// ---------------------------------------------------------------------------
extern "C" void kernel_launch(void* const* d_in, const int* in_sizes, int n_in,
                              void* d_out, int out_size, void* d_ws, size_t ws_size,
                              hipStream_t stream) {
    const float* query = (const float*)d_in[0];
    const float* key   = (const float*)d_in[1];
    const float* value = (const float*)d_in[2];
    const float* Wq = (const float*)d_in[3];
    const float* bq = (const float*)d_in[4];
    const float* Wk = (const float*)d_in[5];
    const float* bk = (const float*)d_in[6];
    const float* Wv = (const float*)d_in[7];
    const float* bv = (const float*)d_in[8];
    const float* Wo = (const float*)d_in[9];
    const float* bo = (const float*)d_in[10];

    float* out = (float*)d_out;                         // [4,1024,1024]
    float* meanOut = out + (size_t)BATCH * SQL * EMBED; // [4,1024,2048]

    u16* Qhi = (u16*)d_ws;                              // [4096][1024] bf16 (aliased by Att)
    u16* Qlo = Qhi + (size_t)4096 * 1024;
    u16* Khi = Qlo + (size_t)4096 * 1024;               // [8192][1024]
    u16* Klo = Khi + (size_t)8192 * 1024;
    u16* VTw = Klo + (size_t)8192 * 1024;               // [1024][8192] (V^T)
    u16* Att = Qhi;                                     // alias: per-head cols, disjoint lifetimes

    gemm_mfma<1, 0, 1><<<dim3(8, 32), 256, 0, stream>>>(query, Wq, bq, Qhi, Qlo, 4096, 1024);
    gemm_mfma<1, 0, 1><<<dim3(8, 64), 256, 0, stream>>>(key, Wk, bk, Khi, Klo, 8192, 1024);
    gemm_mfma<0, 0, 2><<<dim3(64, 8), 256, 0, stream>>>(Wv, value, bv, VTw, nullptr, 1024, 8192);
    attn_mfma<<<dim3(256), dim3(512), 0, stream>>>(Qhi, Qlo, Khi, Klo, VTw, Att, meanOut);
    gemm_mfma<0, 1, 0><<<dim3(8, 32), 256, 0, stream>>>(Att, Wo, bo, out, nullptr, 4096, 1024);
}